// Round 5
// baseline (748.303 us; speedup 1.0000x reference)
//
#include <hip/hip_runtime.h>
#include <math.h>

#define V 7
#define OPD 48
#define HID 96
#define GD 128
#define NGATE 34
#define NONE_OP 3
#define NB 8

typedef unsigned short u16;
typedef unsigned int u32;
typedef _Float16 f16;
typedef __attribute__((ext_vector_type(4))) _Float16 f16x4;
typedef __attribute__((ext_vector_type(8))) _Float16 f16x8;
typedef __attribute__((ext_vector_type(4))) float f32x4;

#define RSCALE 2048.0f
#define RINV   (1.0f/2048.0f)

// ---- workspace byte offsets ----
#define WS_GATES   0u        // [5][34][128] f32
#define WS_SUP0T   87040u    // [128 cols][8 v] f32 (transposed, v=7 zero)
#define WS_GWH     91136u    // [4][128 n][128 k] f16 hi
#define WS_GWL     222208u   // lo * 2048
#define WS_W0H     353280u   // [208][128] f16
#define WS_W0L     406528u
#define WS_W1H     459776u   // [208][224] f16
#define WS_W1L     552960u
#define WS_W2H     646144u
#define WS_W2L     739328u

// ---- LDS byte offsets (dynamic, 34816 total -> 4 blocks/CU) ----
#define S_YH   0u        // [64][128] f16, sw256 (rows = slot*8+v)
#define S_YL   16384u
#define S_SUPT 0u        // ALIAS over Y: [128 cols][64 rows] f32, ssw
#define S_ADJ  32768u    // [8][7][8] f32
#define S_GI   34560u    // [8][8] int
#define S_TOTAL 34816u
// post-GCN aliases inside the Y region:
#define S_ZH   0u        // [16][128] f16, sw256 (rows 8-15 zeroed)
#define S_ZL   4096u
#define S_A1H  8192u     // [16][256] f16, sw512
#define S_A1L  16384u
#define S_A2H  24576u    // hi only (L2 is 2-pass)

__device__ __forceinline__ u32 sw256(u32 row, u32 kb) { return row * 256u + (kb ^ ((row & 7u) << 4)); }
__device__ __forceinline__ u32 sw512(u32 row, u32 kb) { return row * 512u + (kb ^ ((row & 7u) << 4)); }
__device__ __forceinline__ u32 ssw(u32 col, u32 rb) { return col * 256u + (rb ^ (((col ^ (col >> 3)) & 7u) << 4)); }

#define MFMA(a, b, c) __builtin_amdgcn_mfma_f32_16x16x32_f16(a, b, c, 0, 0, 0)

// ===========================================================================
// Precompute: gate tables, transposed support0, split/transposed f16 weights.
// ===========================================================================
__global__ __launch_bounds__(256) void precompute_kernel(
    const float* __restrict__ op_tbl, const float* __restrict__ in_op,
    const float* __restrict__ out_op, const float* __restrict__ in_node,
    const float* __restrict__ other_node, const float* __restrict__ xh_W,
    const float* __restrict__ xh_b, const float* __restrict__ g0W,
    const float* __restrict__ g0attW, const float* __restrict__ g0attb,
    const float* __restrict__ gattW, const float* __restrict__ gattb,
    const float* __restrict__ gW, const float* __restrict__ m0W,
    const float* __restrict__ m1W, const float* __restrict__ m2W,
    char* __restrict__ ws)
{
  const int blk = blockIdx.x, tid = threadIdx.x;
  float* gates = (float*)(ws + WS_GATES);
  float* sup0T = (float*)(ws + WS_SUP0T);
  if (blk < 85) {                       // 170 gate rows, 2 per block
    const int row = blk * 2 + (tid >> 7);
    const int c = tid & 127;
    const int l = row / NGATE, e = row % NGATE;
    const float* emb = (e < 32) ? (op_tbl + e * OPD) : (e == 32 ? in_op : out_op);
    const float* aW = (l == 0) ? g0attW : (gattW + (size_t)(l - 1) * OPD * GD);
    const float* ab = (l == 0) ? g0attb : (gattb + (l - 1) * GD);
    float acc = ab[c];
    for (int j = 0; j < OPD; j++) acc += emb[j] * aW[j * GD + c];
    gates[(size_t)row * GD + c] = 1.0f / (1.0f + expf(-acc));
  } else if (blk == 85) {               // support0 -> transposed [col][8]
    __shared__ float x[V * HID];
    for (int i = tid; i < V * HID; i += 256) {
      const int v = i / HID, h = i % HID;
      const float* emb = (v == 0) ? in_node : other_node;
      float acc = xh_b[h];
      for (int j = 0; j < 48; j++) acc += emb[j] * xh_W[j * HID + h];
      x[i] = acc;
    }
    __syncthreads();
    for (int i = tid; i < V * GD; i += 256) {
      const int v = i / GD, c = i % GD;
      float acc = 0.f;
      for (int h = 0; h < HID; h++) acc += x[v * HID + h] * g0W[h * GD + c];
      sup0T[c * 8 + v] = acc;
    }
    for (int i = tid; i < GD; i += 256) sup0T[i * 8 + 7] = 0.f;
  } else {                              // weight split+transpose (f16 hi/lo)
    for (int idx = (blk - 86) * 256 + tid; idx < 185344; idx += 128 * 256) {
      float w; f16 *ph, *pl;
      if (idx < 65536) {
        const int l = idx >> 14, rem = idx & 16383;
        const int n = rem >> 7, k = rem & 127;
        w = gW[(size_t)l * 16384 + k * 128 + n];
        ph = (f16*)(ws + WS_GWH) + idx; pl = (f16*)(ws + WS_GWL) + idx;
      } else if (idx < 92160) {
        const int j = idx - 65536, n = j >> 7, k = j & 127;
        w = (n < 200) ? m0W[(size_t)k * 200 + n] : 0.f;
        ph = (f16*)(ws + WS_W0H) + j; pl = (f16*)(ws + WS_W0L) + j;
      } else if (idx < 138752) {
        const int j = idx - 92160, n = j / 224, k = j % 224;
        w = (n < 200 && k < 200) ? m1W[(size_t)k * 200 + n] : 0.f;
        ph = (f16*)(ws + WS_W1H) + j; pl = (f16*)(ws + WS_W1L) + j;
      } else {
        const int j = idx - 138752, n = j / 224, k = j % 224;
        w = (n < 200 && k < 200) ? m2W[(size_t)k * 200 + n] : 0.f;
        ph = (f16*)(ws + WS_W2H) + j; pl = (f16*)(ws + WS_W2L) + j;
      }
      const f16 h = (f16)w;
      *ph = h;
      *pl = (f16)((w - (float)h) * RSCALE);
    }
  }
}

// ===========================================================================
// Main fused kernel. 256 threads, 8 slots/block, row = s*8 + v (M=64).
// ===========================================================================
__global__ __launch_bounds__(256, 4) void gin_main_kernel(
    const int* __restrict__ x_ops, const float* __restrict__ x_adj,
    const char* __restrict__ ws,
    const float* __restrict__ g0_bias, const float* __restrict__ gcn_bias,
    const float* __restrict__ m0b, const float* __restrict__ m1b,
    const float* __restrict__ m2b, const float* __restrict__ m3W,
    const float* __restrict__ m3b, float* __restrict__ out)
{
  extern __shared__ char smem[];
  const int tid = threadIdx.x;
  const int bbase = blockIdx.x * NB;
  const float* gates_ws = (const float*)(ws + WS_GATES);
  const float* sup0T = (const float*)(ws + WS_SUP0T);
  const f16* GWH = (const f16*)(ws + WS_GWH);
  const f16* GWL = (const f16*)(ws + WS_GWL);
  const f16* W0H = (const f16*)(ws + WS_W0H);
  const f16* W0L = (const f16*)(ws + WS_W0L);
  const f16* W1H = (const f16*)(ws + WS_W1H);
  const f16* W1L = (const f16*)(ws + WS_W1L);
  const f16* W2H = (const f16*)(ws + WS_W2H);
  const f16* W2L = (const f16*)(ws + WS_W2L);

  // ---- prologue: adj^T + gate indices ----
  for (int i = tid; i < NB * 56; i += 256) {
    const int s = i / 56, r = i % 56, v = r >> 3, w = r & 7;
    ((float*)(smem + S_ADJ))[i] = (w < 7) ? x_adj[(size_t)(bbase + s) * 49 + w * 7 + v] : 0.f;
  }
  if (tid < 64) {
    const int s = tid >> 3, v = tid & 7;
    const int g = (v == 0) ? 32 : (v == 6) ? 33 : (v == 7) ? 0
                : x_ops[(size_t)(bbase + s) * 7 + v];
    ((int*)(smem + S_GI))[tid] = g;
  }
  __syncthreads();

  const int lane = tid & 63, wave = tid >> 6;
  const int lrow = lane & 15, lq = lane >> 4;
  const int ms = tid >> 5;            // mix: slot 0..7
  const int colbase = (tid & 31) * 4; // mix: 4 cols per thread

  // =================== GCN layers ===================
  for (int l = 0; l < 5; l++) {
    if (l > 0) {
      const f16* wh = GWH + (l - 1) * 16384;
      const f16* wl = GWL + (l - 1) * 16384;
      f32x4 acc0[4][2], acc1[4][2];
#pragma unroll
      for (int t = 0; t < 4; t++)
#pragma unroll
        for (int nt = 0; nt < 2; nt++) {
          acc0[t][nt] = (f32x4){0.f, 0.f, 0.f, 0.f};
          acc1[t][nt] = (f32x4){0.f, 0.f, 0.f, 0.f};
        }
#pragma unroll
      for (int ks = 0; ks < 4; ks++) {
        f16x8 bh[2], bl[2];
#pragma unroll
        for (int nt = 0; nt < 2; nt++) {
          const int eo = (wave * 32 + nt * 16 + lrow) * 128 + ks * 32 + lq * 8;
          bh[nt] = *(const f16x8*)(wh + eo);
          bl[nt] = *(const f16x8*)(wl + eo);
        }
#pragma unroll
        for (int t = 0; t < 4; t++) {
          const u32 off = sw256((u32)(t * 16 + lrow), (u32)(ks * 64 + lq * 16));
          const f16x8 ah = *(const f16x8*)(smem + S_YH + off);
          const f16x8 al = *(const f16x8*)(smem + S_YL + off);
#pragma unroll
          for (int nt = 0; nt < 2; nt++) {
            acc0[t][nt] = MFMA(ah, bh[nt], acc0[t][nt]);
            acc1[t][nt] = MFMA(ah, bl[nt], acc1[t][nt]);
            acc1[t][nt] = MFMA(al, bh[nt], acc1[t][nt]);
          }
        }
      }
      __syncthreads();   // all waves done reading Y; SUPT may clobber it
#pragma unroll
      for (int t = 0; t < 4; t++)
#pragma unroll
        for (int nt = 0; nt < 2; nt++) {
          const u32 col = (u32)(wave * 32 + nt * 16 + lrow);
          f32x4 vv;
#pragma unroll
          for (int r = 0; r < 4; r++) vv[r] = acc0[t][nt][r] + acc1[t][nt][r] * RINV;
          *(f32x4*)(smem + S_SUPT + ssw(col, (u32)(t * 64 + lq * 16))) = vv;
        }
      __syncthreads();
    }

    // ---- phase C: load support for (slot, 4 cols) into regs ----
    f32x4 sa[4], sb[4];
    if (l == 0) {
#pragma unroll
      for (int c = 0; c < 4; c++) {
        const float* p = sup0T + (size_t)(colbase + c) * 8;
        sa[c] = *(const f32x4*)p;
        sb[c] = *(const f32x4*)(p + 4);
      }
    } else {
#pragma unroll
      for (int c = 0; c < 4; c++) {
        const u32 col = (u32)(colbase + c);
        sa[c] = *(const f32x4*)(smem + S_SUPT + ssw(col, (u32)(ms * 32)));
        sb[c] = *(const f32x4*)(smem + S_SUPT + ssw(col, (u32)(ms * 32 + 16)));
      }
      __syncthreads();   // SUPT in regs; Y region may be rewritten
    }

    // ---- phase D: adjmix + gate + residual + bias ----
    {
      const float* bias_l = (l == 0) ? g0_bias : gcn_bias + (l - 1) * GD;
      const f32x4 bb = *(const f32x4*)(bias_l + colbase);
      const int* giv = (const int*)(smem + S_GI) + ms * 8;
      float zacc[4];
#pragma unroll
      for (int c = 0; c < 4; c++) zacc[c] = 0.f;
#pragma unroll
      for (int v = 0; v < 7; v++) {
        const f32x4 a0 = *(const f32x4*)(smem + S_ADJ + (ms * 56 + v * 8) * 4);
        const f32x4 a1 = *(const f32x4*)(smem + S_ADJ + (ms * 56 + v * 8) * 4 + 16);
        const int gidx = giv[v];
        const f32x4 gg = *(const f32x4*)(gates_ws + ((size_t)l * NGATE + gidx) * GD + colbase);
        float y[4];
#pragma unroll
        for (int c = 0; c < 4; c++) {
          const float t = a0[0] * sa[c][0] + a0[1] * sa[c][1] + a0[2] * sa[c][2] + a0[3] * sa[c][3]
                        + a1[0] * sb[c][0] + a1[1] * sb[c][1] + a1[2] * sb[c][2];
          const float sv = (v < 4) ? sa[c][v] : sb[c][v - 4];
          y[c] = gg[c] * t + sv + bb[c];
        }
        if (l < 4) {
          union { f16x4 v4; f16 e[4]; } ph, pl;
#pragma unroll
          for (int c = 0; c < 4; c++) {
            const float r = fmaxf(y[c], 0.f);
            const f16 h = (f16)r;
            ph.e[c] = h;
            pl.e[c] = (f16)((r - (float)h) * RSCALE);
          }
          const u32 yo = sw256((u32)(ms * 8 + v), (u32)(colbase * 2));
          *(f16x4*)(smem + S_YH + yo) = ph.v4;
          *(f16x4*)(smem + S_YL + yo) = pl.v4;
        } else {
          if ((v == 6) || (v >= 1 && gidx != NONE_OP))
#pragma unroll
            for (int c = 0; c < 4; c++) zacc[c] += y[c];
        }
      }
      if (l == 4) {
        union { f16x4 v4; f16 e[4]; } ph, pl;
#pragma unroll
        for (int c = 0; c < 4; c++) {
          const float z = zacc[c] * (1.f / 6.f);
          const f16 h = (f16)z;
          ph.e[c] = h;
          pl.e[c] = (f16)((z - (float)h) * RSCALE);
        }
        const u32 zo = sw256((u32)ms, (u32)(colbase * 2));
        *(f16x4*)(smem + S_ZH + zo) = ph.v4;
        *(f16x4*)(smem + S_ZL + zo) = pl.v4;
        // Zero stale-alias garbage that MFMA K-dims / M-rows will read:
        // Z pad rows 8-15 (hi+lo) and the whole A1H/A1L/A2H act region.
        // (Stale SUPT f32 bytes reinterpreted as f16 can be Inf/NaN; Inf*0
        //  on zero-padded weight cols would poison valid accumulators.)
        for (int i = tid; i < 512; i += 256) {
          ((u32*)(smem + S_ZH + 2048u))[i] = 0u;   // ZH rows 8-15
          ((u32*)(smem + S_ZL + 2048u))[i] = 0u;   // ZL rows 8-15
        }
        for (int i = tid; i < 6144; i += 256)
          ((u32*)(smem + S_A1H))[i] = 0u;          // A1H, A1L, A2H (24 KB)
      }
    }
    __syncthreads();
  }

  // =================== MLP ===================
  // L0: Z(16x128) @ W0t -> A1 (hi+lo)
  {
    f32x4 macc0[4], macc1[4];
#pragma unroll
    for (int i = 0; i < 4; i++) { macc0[i] = (f32x4){0.f,0.f,0.f,0.f}; macc1[i] = (f32x4){0.f,0.f,0.f,0.f}; }
#pragma unroll
    for (int ks = 0; ks < 4; ks++) {
      const u32 off = sw256((u32)lrow, (u32)(ks * 64 + lq * 16));
      const f16x8 zh = *(const f16x8*)(smem + S_ZH + off);
      const f16x8 zl = *(const f16x8*)(smem + S_ZL + off);
#pragma unroll
      for (int i = 0; i < 4; i++) {
        const int nt = wave + i * 4;
        if (nt < 13) {
          const int eo = (nt * 16 + lrow) * 128 + ks * 32 + lq * 8;
          const f16x8 wh8 = *(const f16x8*)(W0H + eo);
          const f16x8 wl8 = *(const f16x8*)(W0L + eo);
          macc0[i] = MFMA(zh, wh8, macc0[i]);
          macc1[i] = MFMA(zh, wl8, macc1[i]);
          macc1[i] = MFMA(zl, wh8, macc1[i]);
        }
      }
    }
#pragma unroll
    for (int i = 0; i < 4; i++) {
      const int nt = wave + i * 4;
      if (nt < 13) {
        const int col = nt * 16 + lrow;
        const float b = (col < 200) ? m0b[col] : 0.f;
#pragma unroll
        for (int r = 0; r < 4; r++) {
          const float a = fmaxf(macc0[i][r] + macc1[i][r] * RINV + b, 0.f);
          const f16 h = (f16)a;
          const u32 off = sw512((u32)(lq * 4 + r), (u32)(2 * col));
          *(f16*)(smem + S_A1H + off) = h;
          *(f16*)(smem + S_A1L + off) = (f16)((a - (float)h) * RSCALE);
        }
      }
    }
  }
  __syncthreads();
  // L1: A1(16x224) @ W1t -> A2 (hi only)
  {
    f32x4 macc0[4], macc1[4];
#pragma unroll
    for (int i = 0; i < 4; i++) { macc0[i] = (f32x4){0.f,0.f,0.f,0.f}; macc1[i] = (f32x4){0.f,0.f,0.f,0.f}; }
#pragma unroll
    for (int ks = 0; ks < 7; ks++) {
      const u32 off = sw512((u32)lrow, (u32)(ks * 64 + lq * 16));
      const f16x8 ah = *(const f16x8*)(smem + S_A1H + off);
      const f16x8 al = *(const f16x8*)(smem + S_A1L + off);
#pragma unroll
      for (int i = 0; i < 4; i++) {
        const int nt = wave + i * 4;
        if (nt < 13) {
          const int eo = (nt * 16 + lrow) * 224 + ks * 32 + lq * 8;
          const f16x8 wh8 = *(const f16x8*)(W1H + eo);
          const f16x8 wl8 = *(const f16x8*)(W1L + eo);
          macc0[i] = MFMA(ah, wh8, macc0[i]);
          macc1[i] = MFMA(ah, wl8, macc1[i]);
          macc1[i] = MFMA(al, wh8, macc1[i]);
        }
      }
    }
#pragma unroll
    for (int i = 0; i < 4; i++) {
      const int nt = wave + i * 4;
      if (nt < 13) {
        const int col = nt * 16 + lrow;
        const float b = (col < 200) ? m1b[col] : 0.f;
#pragma unroll
        for (int r = 0; r < 4; r++) {
          const float a = fmaxf(macc0[i][r] + macc1[i][r] * RINV + b, 0.f);
          const u32 off = sw512((u32)(lq * 4 + r), (u32)(2 * col));
          *(f16*)(smem + S_A2H + off) = (f16)a;
        }
      }
    }
  }
  __syncthreads();
  // L2: A2(hi only) @ W2t (2-pass) -> A3 (reuses A1H region)
  {
    f32x4 macc0[4], macc1[4];
#pragma unroll
    for (int i = 0; i < 4; i++) { macc0[i] = (f32x4){0.f,0.f,0.f,0.f}; macc1[i] = (f32x4){0.f,0.f,0.f,0.f}; }
#pragma unroll
    for (int ks = 0; ks < 7; ks++) {
      const u32 off = sw512((u32)lrow, (u32)(ks * 64 + lq * 16));
      const f16x8 ah = *(const f16x8*)(smem + S_A2H + off);
#pragma unroll
      for (int i = 0; i < 4; i++) {
        const int nt = wave + i * 4;
        if (nt < 13) {
          const int eo = (nt * 16 + lrow) * 224 + ks * 32 + lq * 8;
          const f16x8 wh8 = *(const f16x8*)(W2H + eo);
          const f16x8 wl8 = *(const f16x8*)(W2L + eo);
          macc0[i] = MFMA(ah, wh8, macc0[i]);
          macc1[i] = MFMA(ah, wl8, macc1[i]);
        }
      }
    }
    __syncthreads();   // all waves done reading A2/A1 before A3 overwrites A1H
#pragma unroll
    for (int i = 0; i < 4; i++) {
      const int nt = wave + i * 4;
      if (nt < 13) {
        const int col = nt * 16 + lrow;
        const float b = (col < 200) ? m2b[col] : 0.f;
#pragma unroll
        for (int r = 0; r < 4; r++) {
          const float a = fmaxf(macc0[i][r] + macc1[i][r] * RINV + b, 0.f);
          const u32 off = sw512((u32)(lq * 4 + r), (u32)(2 * col));
          *(f16*)(smem + S_A1H + off) = (f16)a;
        }
      }
    }
  }
  __syncthreads();
  // final: out[s] = A3[s] . m3W + b
  {
    const int kl = tid & 31;
    float p = 0.f;
    for (int k = kl; k < 200; k += 32) {
      const u32 off = sw512((u32)ms, (u32)(2 * k));
      p += (float)(*(const f16*)(smem + S_A1H + off)) * m3W[k];
    }
#pragma unroll
    for (int d = 16; d > 0; d >>= 1) p += __shfl_down(p, d, 32);
    if (kl == 0) out[bbase + ms] = p + m3b[0];
  }
}

// ===========================================================================
extern "C" void kernel_launch(void* const* d_in, const int* in_sizes, int n_in,
                              void* d_out, int out_size, void* d_ws, size_t ws_size,
                              hipStream_t stream) {
  const int*   x_ops    = (const int*)  d_in[0];
  const float* x_adj    = (const float*)d_in[1];
  const float* op_tbl   = (const float*)d_in[3];
  const float* in_op    = (const float*)d_in[4];
  const float* out_op   = (const float*)d_in[5];
  const float* in_node  = (const float*)d_in[6];
  const float* oth_node = (const float*)d_in[7];
  const float* xh_W     = (const float*)d_in[8];
  const float* xh_b     = (const float*)d_in[9];
  const float* g0W      = (const float*)d_in[10];
  const float* g0attW   = (const float*)d_in[11];
  const float* g0attb   = (const float*)d_in[12];
  const float* g0bias   = (const float*)d_in[13];
  const float* gW       = (const float*)d_in[14];
  const float* gattW    = (const float*)d_in[15];
  const float* gattb    = (const float*)d_in[16];
  const float* gbias    = (const float*)d_in[17];
  const float* m0W = (const float*)d_in[18], *m0b = (const float*)d_in[19];
  const float* m1W = (const float*)d_in[20], *m1b = (const float*)d_in[21];
  const float* m2W = (const float*)d_in[22], *m2b = (const float*)d_in[23];
  const float* m3W = (const float*)d_in[24], *m3b = (const float*)d_in[25];
  float* out = (float*)d_out;
  char* ws = (char*)d_ws;
  (void)ws_size; (void)n_in; (void)out_size;

  const int B = in_sizes[0] / V;
  const int nblk = B / NB;

  hipFuncSetAttribute((const void*)gin_main_kernel,
                      hipFuncAttributeMaxDynamicSharedMemorySize, (int)S_TOTAL);

  hipLaunchKernelGGL(precompute_kernel, dim3(214), dim3(256), 0, stream,
                     op_tbl, in_op, out_op, in_node, oth_node, xh_W, xh_b,
                     g0W, g0attW, g0attb, gattW, gattb, gW, m0W, m1W, m2W, ws);
  hipLaunchKernelGGL(gin_main_kernel, dim3(nblk), dim3(256), (int)S_TOTAL, stream,
                     x_ops, x_adj, (const char*)ws, g0bias, gbias,
                     m0b, m1b, m2b, m3W, m3b, out);
}

// Round 6
// 658.243 us; speedup vs baseline: 1.1368x; 1.1368x over previous
//
#include <hip/hip_runtime.h>
#include <math.h>

#define V 7
#define OPD 48
#define HID 96
#define GD 128
#define NGATE 34
#define NONE_OP 3
#define NB 8

typedef unsigned short u16;
typedef unsigned int u32;
typedef _Float16 f16;
typedef __attribute__((ext_vector_type(4))) _Float16 f16x4;
typedef __attribute__((ext_vector_type(8))) _Float16 f16x8;
typedef __attribute__((ext_vector_type(4))) float f32x4;

#define RSCALE 2048.0f
#define RINV   (1.0f/2048.0f)

// ---- workspace byte offsets ----
#define WS_GATES   0u        // [5][34][128] f32
#define WS_SUP0T   87040u    // [128 cols][8 v] f32 (transposed, v=7 zero)
#define WS_GWH     91136u    // [4][128 n][128 k] f16 hi
#define WS_GWL     222208u   // lo * 2048
#define WS_W0H     353280u   // [208][128] f16
#define WS_W0L     406528u
#define WS_W1H     459776u   // [208][224] f16
#define WS_W1L     552960u
#define WS_W2H     646144u
#define WS_W2L     739328u

// ---- LDS byte offsets (dynamic, 34816 total) ----
#define S_YH   0u        // [64][128] f16, sw256 (rows = slot*8+v)
#define S_YL   16384u
#define S_SUPT 0u        // ALIAS over Y: [128 cols][64 rows] f32, ssw
#define S_ADJ  32768u    // [8][7][8] f32
#define S_GI   34560u    // [8][8] int
#define S_TOTAL 34816u
// post-GCN aliases inside the Y region:
#define S_ZH   0u        // [16][128] f16, sw256 (rows 8-15 zeroed)
#define S_ZL   4096u
#define S_A1H  8192u     // [16][256] f16, sw512
#define S_A1L  16384u
#define S_A2H  24576u    // hi only (L2 is 2-pass)

__device__ __forceinline__ u32 sw256(u32 row, u32 kb) { return row * 256u + (kb ^ ((row & 7u) << 4)); }
__device__ __forceinline__ u32 sw512(u32 row, u32 kb) { return row * 512u + (kb ^ ((row & 7u) << 4)); }
__device__ __forceinline__ u32 ssw(u32 col, u32 rb) { return col * 256u + (rb ^ (((col ^ (col >> 3)) & 7u) << 4)); }

#define MFMA(a, b, c) __builtin_amdgcn_mfma_f32_16x16x32_f16(a, b, c, 0, 0, 0)

// ===========================================================================
// Precompute: gate tables, transposed support0, split/transposed f16 weights.
// ===========================================================================
__global__ __launch_bounds__(256) void precompute_kernel(
    const float* __restrict__ op_tbl, const float* __restrict__ in_op,
    const float* __restrict__ out_op, const float* __restrict__ in_node,
    const float* __restrict__ other_node, const float* __restrict__ xh_W,
    const float* __restrict__ xh_b, const float* __restrict__ g0W,
    const float* __restrict__ g0attW, const float* __restrict__ g0attb,
    const float* __restrict__ gattW, const float* __restrict__ gattb,
    const float* __restrict__ gW, const float* __restrict__ m0W,
    const float* __restrict__ m1W, const float* __restrict__ m2W,
    char* __restrict__ ws)
{
  const int blk = blockIdx.x, tid = threadIdx.x;
  float* gates = (float*)(ws + WS_GATES);
  float* sup0T = (float*)(ws + WS_SUP0T);
  if (blk < 85) {                       // 170 gate rows, 2 per block
    const int row = blk * 2 + (tid >> 7);
    const int c = tid & 127;
    const int l = row / NGATE, e = row % NGATE;
    const float* emb = (e < 32) ? (op_tbl + e * OPD) : (e == 32 ? in_op : out_op);
    const float* aW = (l == 0) ? g0attW : (gattW + (size_t)(l - 1) * OPD * GD);
    const float* ab = (l == 0) ? g0attb : (gattb + (l - 1) * GD);
    float acc = ab[c];
    for (int j = 0; j < OPD; j++) acc += emb[j] * aW[j * GD + c];
    gates[(size_t)row * GD + c] = 1.0f / (1.0f + expf(-acc));
  } else if (blk == 85) {               // support0 -> transposed [col][8]
    __shared__ float x[V * HID];
    for (int i = tid; i < V * HID; i += 256) {
      const int v = i / HID, h = i % HID;
      const float* emb = (v == 0) ? in_node : other_node;
      float acc = xh_b[h];
      for (int j = 0; j < 48; j++) acc += emb[j] * xh_W[j * HID + h];
      x[i] = acc;
    }
    __syncthreads();
    for (int i = tid; i < V * GD; i += 256) {
      const int v = i / GD, c = i % GD;
      float acc = 0.f;
      for (int h = 0; h < HID; h++) acc += x[v * HID + h] * g0W[h * GD + c];
      sup0T[c * 8 + v] = acc;
    }
    for (int i = tid; i < GD; i += 256) sup0T[i * 8 + 7] = 0.f;
  } else {                              // weight split+transpose (f16 hi/lo)
    for (int idx = (blk - 86) * 256 + tid; idx < 185344; idx += 128 * 256) {
      float w; f16 *ph, *pl;
      if (idx < 65536) {
        const int l = idx >> 14, rem = idx & 16383;
        const int n = rem >> 7, k = rem & 127;
        w = gW[(size_t)l * 16384 + k * 128 + n];
        ph = (f16*)(ws + WS_GWH) + idx; pl = (f16*)(ws + WS_GWL) + idx;
      } else if (idx < 92160) {
        const int j = idx - 65536, n = j >> 7, k = j & 127;
        w = (n < 200) ? m0W[(size_t)k * 200 + n] : 0.f;
        ph = (f16*)(ws + WS_W0H) + j; pl = (f16*)(ws + WS_W0L) + j;
      } else if (idx < 138752) {
        const int j = idx - 92160, n = j / 224, k = j % 224;
        w = (n < 200 && k < 200) ? m1W[(size_t)k * 200 + n] : 0.f;
        ph = (f16*)(ws + WS_W1H) + j; pl = (f16*)(ws + WS_W1L) + j;
      } else {
        const int j = idx - 138752, n = j / 224, k = j % 224;
        w = (n < 200 && k < 200) ? m2W[(size_t)k * 200 + n] : 0.f;
        ph = (f16*)(ws + WS_W2H) + j; pl = (f16*)(ws + WS_W2L) + j;
      }
      const f16 h = (f16)w;
      *ph = h;
      *pl = (f16)((w - (float)h) * RSCALE);
    }
  }
}

// ===========================================================================
// Main fused kernel. 256 threads, 8 slots/block, row = s*8 + v (M=64).
// launch_bounds (256,3): VGPR cap ~170 — round 5's (256,4) capped at 64 and
// spilled 430 MB/dispatch of scratch to HBM (FETCH 174 MB / WRITE 270 MB).
// ===========================================================================
__global__ __launch_bounds__(256, 3) void gin_main_kernel(
    const int* __restrict__ x_ops, const float* __restrict__ x_adj,
    const char* __restrict__ ws,
    const float* __restrict__ g0_bias, const float* __restrict__ gcn_bias,
    const float* __restrict__ m0b, const float* __restrict__ m1b,
    const float* __restrict__ m2b, const float* __restrict__ m3W,
    const float* __restrict__ m3b, float* __restrict__ out)
{
  extern __shared__ char smem[];
  const int tid = threadIdx.x;
  const int bbase = blockIdx.x * NB;
  const float* gates_ws = (const float*)(ws + WS_GATES);
  const float* sup0T = (const float*)(ws + WS_SUP0T);
  const f16* GWH = (const f16*)(ws + WS_GWH);
  const f16* GWL = (const f16*)(ws + WS_GWL);
  const f16* W0H = (const f16*)(ws + WS_W0H);
  const f16* W0L = (const f16*)(ws + WS_W0L);
  const f16* W1H = (const f16*)(ws + WS_W1H);
  const f16* W1L = (const f16*)(ws + WS_W1L);
  const f16* W2H = (const f16*)(ws + WS_W2H);
  const f16* W2L = (const f16*)(ws + WS_W2L);

  // ---- prologue: adj^T + gate indices ----
  for (int i = tid; i < NB * 56; i += 256) {
    const int s = i / 56, r = i % 56, v = r >> 3, w = r & 7;
    ((float*)(smem + S_ADJ))[i] = (w < 7) ? x_adj[(size_t)(bbase + s) * 49 + w * 7 + v] : 0.f;
  }
  if (tid < 64) {
    const int s = tid >> 3, v = tid & 7;
    const int g = (v == 0) ? 32 : (v == 6) ? 33 : (v == 7) ? 0
                : x_ops[(size_t)(bbase + s) * 7 + v];
    ((int*)(smem + S_GI))[tid] = g;
  }
  __syncthreads();

  const int lane = tid & 63, wave = tid >> 6;
  const int lrow = lane & 15, lq = lane >> 4;
  const int ms = tid >> 5;            // mix: slot 0..7
  const int colbase = (tid & 31) * 4; // mix: 4 cols per thread

  // =================== GCN layers ===================
  for (int l = 0; l < 5; l++) {
    if (l > 0) {
      const f16* wh = GWH + (l - 1) * 16384;
      const f16* wl = GWL + (l - 1) * 16384;
      f32x4 acc0[4][2], acc1[4][2];
#pragma unroll
      for (int t = 0; t < 4; t++)
#pragma unroll
        for (int nt = 0; nt < 2; nt++) {
          acc0[t][nt] = (f32x4){0.f, 0.f, 0.f, 0.f};
          acc1[t][nt] = (f32x4){0.f, 0.f, 0.f, 0.f};
        }
#pragma unroll
      for (int ks = 0; ks < 4; ks++) {
        f16x8 bh[2], bl[2];
#pragma unroll
        for (int nt = 0; nt < 2; nt++) {
          const int eo = (wave * 32 + nt * 16 + lrow) * 128 + ks * 32 + lq * 8;
          bh[nt] = *(const f16x8*)(wh + eo);
          bl[nt] = *(const f16x8*)(wl + eo);
        }
#pragma unroll
        for (int t = 0; t < 4; t++) {
          const u32 off = sw256((u32)(t * 16 + lrow), (u32)(ks * 64 + lq * 16));
          const f16x8 ah = *(const f16x8*)(smem + S_YH + off);
          const f16x8 al = *(const f16x8*)(smem + S_YL + off);
#pragma unroll
          for (int nt = 0; nt < 2; nt++) {
            acc0[t][nt] = MFMA(ah, bh[nt], acc0[t][nt]);
            acc1[t][nt] = MFMA(ah, bl[nt], acc1[t][nt]);
            acc1[t][nt] = MFMA(al, bh[nt], acc1[t][nt]);
          }
        }
      }
      __syncthreads();   // all waves done reading Y; SUPT may clobber it
#pragma unroll
      for (int t = 0; t < 4; t++)
#pragma unroll
        for (int nt = 0; nt < 2; nt++) {
          const u32 col = (u32)(wave * 32 + nt * 16 + lrow);
          f32x4 vv;
#pragma unroll
          for (int r = 0; r < 4; r++) vv[r] = acc0[t][nt][r] + acc1[t][nt][r] * RINV;
          *(f32x4*)(smem + S_SUPT + ssw(col, (u32)(t * 64 + lq * 16))) = vv;
        }
      __syncthreads();
    }

    // ---- phase C: load support for (slot, 4 cols) into regs ----
    f32x4 sa[4], sb[4];
    if (l == 0) {
#pragma unroll
      for (int c = 0; c < 4; c++) {
        const float* p = sup0T + (size_t)(colbase + c) * 8;
        sa[c] = *(const f32x4*)p;
        sb[c] = *(const f32x4*)(p + 4);
      }
    } else {
#pragma unroll
      for (int c = 0; c < 4; c++) {
        const u32 col = (u32)(colbase + c);
        sa[c] = *(const f32x4*)(smem + S_SUPT + ssw(col, (u32)(ms * 32)));
        sb[c] = *(const f32x4*)(smem + S_SUPT + ssw(col, (u32)(ms * 32 + 16)));
      }
      __syncthreads();   // SUPT in regs; Y region may be rewritten
    }

    // ---- phase D: adjmix + gate + residual + bias ----
    {
      const float* bias_l = (l == 0) ? g0_bias : gcn_bias + (l - 1) * GD;
      const f32x4 bb = *(const f32x4*)(bias_l + colbase);
      const int* giv = (const int*)(smem + S_GI) + ms * 8;
      float zacc[4];
#pragma unroll
      for (int c = 0; c < 4; c++) zacc[c] = 0.f;
#pragma unroll
      for (int v = 0; v < 7; v++) {
        const f32x4 a0 = *(const f32x4*)(smem + S_ADJ + (ms * 56 + v * 8) * 4);
        const f32x4 a1 = *(const f32x4*)(smem + S_ADJ + (ms * 56 + v * 8) * 4 + 16);
        const int gidx = giv[v];
        const f32x4 gg = *(const f32x4*)(gates_ws + ((size_t)l * NGATE + gidx) * GD + colbase);
        float y[4];
#pragma unroll
        for (int c = 0; c < 4; c++) {
          const float t = a0[0] * sa[c][0] + a0[1] * sa[c][1] + a0[2] * sa[c][2] + a0[3] * sa[c][3]
                        + a1[0] * sb[c][0] + a1[1] * sb[c][1] + a1[2] * sb[c][2];
          const float sv = (v < 4) ? sa[c][v] : sb[c][v - 4];
          y[c] = gg[c] * t + sv + bb[c];
        }
        if (l < 4) {
          union { f16x4 v4; f16 e[4]; } ph, pl;
#pragma unroll
          for (int c = 0; c < 4; c++) {
            const float r = fmaxf(y[c], 0.f);
            const f16 h = (f16)r;
            ph.e[c] = h;
            pl.e[c] = (f16)((r - (float)h) * RSCALE);
          }
          const u32 yo = sw256((u32)(ms * 8 + v), (u32)(colbase * 2));
          *(f16x4*)(smem + S_YH + yo) = ph.v4;
          *(f16x4*)(smem + S_YL + yo) = pl.v4;
        } else {
          if ((v == 6) || (v >= 1 && gidx != NONE_OP))
#pragma unroll
            for (int c = 0; c < 4; c++) zacc[c] += y[c];
        }
      }
      if (l == 4) {
        union { f16x4 v4; f16 e[4]; } ph, pl;
#pragma unroll
        for (int c = 0; c < 4; c++) {
          const float z = zacc[c] * (1.f / 6.f);
          const f16 h = (f16)z;
          ph.e[c] = h;
          pl.e[c] = (f16)((z - (float)h) * RSCALE);
        }
        const u32 zo = sw256((u32)ms, (u32)(colbase * 2));
        *(f16x4*)(smem + S_ZH + zo) = ph.v4;
        *(f16x4*)(smem + S_ZL + zo) = pl.v4;
        // Zero stale-alias garbage that MFMA K-dims / M-rows will read:
        // Z pad rows 8-15 (hi+lo) and the whole A1H/A1L/A2H act region.
        for (int i = tid; i < 512; i += 256) {
          ((u32*)(smem + S_ZH + 2048u))[i] = 0u;   // ZH rows 8-15
          ((u32*)(smem + S_ZL + 2048u))[i] = 0u;   // ZL rows 8-15
        }
        for (int i = tid; i < 6144; i += 256)
          ((u32*)(smem + S_A1H))[i] = 0u;          // A1H, A1L, A2H (24 KB)
      }
    }
    __syncthreads();
  }

  // =================== MLP ===================
  // L0: Z(16x128) @ W0t -> A1 (hi+lo)
  {
    f32x4 macc0[4], macc1[4];
#pragma unroll
    for (int i = 0; i < 4; i++) { macc0[i] = (f32x4){0.f,0.f,0.f,0.f}; macc1[i] = (f32x4){0.f,0.f,0.f,0.f}; }
#pragma unroll
    for (int ks = 0; ks < 4; ks++) {
      const u32 off = sw256((u32)lrow, (u32)(ks * 64 + lq * 16));
      const f16x8 zh = *(const f16x8*)(smem + S_ZH + off);
      const f16x8 zl = *(const f16x8*)(smem + S_ZL + off);
#pragma unroll
      for (int i = 0; i < 4; i++) {
        const int nt = wave + i * 4;
        if (nt < 13) {
          const int eo = (nt * 16 + lrow) * 128 + ks * 32 + lq * 8;
          const f16x8 wh8 = *(const f16x8*)(W0H + eo);
          const f16x8 wl8 = *(const f16x8*)(W0L + eo);
          macc0[i] = MFMA(zh, wh8, macc0[i]);
          macc1[i] = MFMA(zh, wl8, macc1[i]);
          macc1[i] = MFMA(zl, wh8, macc1[i]);
        }
      }
    }
#pragma unroll
    for (int i = 0; i < 4; i++) {
      const int nt = wave + i * 4;
      if (nt < 13) {
        const int col = nt * 16 + lrow;
        const float b = (col < 200) ? m0b[col] : 0.f;
#pragma unroll
        for (int r = 0; r < 4; r++) {
          const float a = fmaxf(macc0[i][r] + macc1[i][r] * RINV + b, 0.f);
          const f16 h = (f16)a;
          const u32 off = sw512((u32)(lq * 4 + r), (u32)(2 * col));
          *(f16*)(smem + S_A1H + off) = h;
          *(f16*)(smem + S_A1L + off) = (f16)((a - (float)h) * RSCALE);
        }
      }
    }
  }
  __syncthreads();
  // L1: A1(16x224) @ W1t -> A2 (hi only)
  {
    f32x4 macc0[4], macc1[4];
#pragma unroll
    for (int i = 0; i < 4; i++) { macc0[i] = (f32x4){0.f,0.f,0.f,0.f}; macc1[i] = (f32x4){0.f,0.f,0.f,0.f}; }
#pragma unroll
    for (int ks = 0; ks < 7; ks++) {
      const u32 off = sw512((u32)lrow, (u32)(ks * 64 + lq * 16));
      const f16x8 ah = *(const f16x8*)(smem + S_A1H + off);
      const f16x8 al = *(const f16x8*)(smem + S_A1L + off);
#pragma unroll
      for (int i = 0; i < 4; i++) {
        const int nt = wave + i * 4;
        if (nt < 13) {
          const int eo = (nt * 16 + lrow) * 224 + ks * 32 + lq * 8;
          const f16x8 wh8 = *(const f16x8*)(W1H + eo);
          const f16x8 wl8 = *(const f16x8*)(W1L + eo);
          macc0[i] = MFMA(ah, wh8, macc0[i]);
          macc1[i] = MFMA(ah, wl8, macc1[i]);
          macc1[i] = MFMA(al, wh8, macc1[i]);
        }
      }
    }
#pragma unroll
    for (int i = 0; i < 4; i++) {
      const int nt = wave + i * 4;
      if (nt < 13) {
        const int col = nt * 16 + lrow;
        const float b = (col < 200) ? m1b[col] : 0.f;
#pragma unroll
        for (int r = 0; r < 4; r++) {
          const float a = fmaxf(macc0[i][r] + macc1[i][r] * RINV + b, 0.f);
          const u32 off = sw512((u32)(lq * 4 + r), (u32)(2 * col));
          *(f16*)(smem + S_A2H + off) = (f16)a;
        }
      }
    }
  }
  __syncthreads();
  // L2: A2(hi only) @ W2t (2-pass) -> A3 (reuses A1H region)
  {
    f32x4 macc0[4], macc1[4];
#pragma unroll
    for (int i = 0; i < 4; i++) { macc0[i] = (f32x4){0.f,0.f,0.f,0.f}; macc1[i] = (f32x4){0.f,0.f,0.f,0.f}; }
#pragma unroll
    for (int ks = 0; ks < 7; ks++) {
      const u32 off = sw512((u32)lrow, (u32)(ks * 64 + lq * 16));
      const f16x8 ah = *(const f16x8*)(smem + S_A2H + off);
#pragma unroll
      for (int i = 0; i < 4; i++) {
        const int nt = wave + i * 4;
        if (nt < 13) {
          const int eo = (nt * 16 + lrow) * 224 + ks * 32 + lq * 8;
          const f16x8 wh8 = *(const f16x8*)(W2H + eo);
          const f16x8 wl8 = *(const f16x8*)(W2L + eo);
          macc0[i] = MFMA(ah, wh8, macc0[i]);
          macc1[i] = MFMA(ah, wl8, macc1[i]);
        }
      }
    }
    __syncthreads();   // all waves done reading A2/A1 before A3 overwrites A1H
#pragma unroll
    for (int i = 0; i < 4; i++) {
      const int nt = wave + i * 4;
      if (nt < 13) {
        const int col = nt * 16 + lrow;
        const float b = (col < 200) ? m2b[col] : 0.f;
#pragma unroll
        for (int r = 0; r < 4; r++) {
          const float a = fmaxf(macc0[i][r] + macc1[i][r] * RINV + b, 0.f);
          const u32 off = sw512((u32)(lq * 4 + r), (u32)(2 * col));
          *(f16*)(smem + S_A1H + off) = (f16)a;
        }
      }
    }
  }
  __syncthreads();
  // final: out[s] = A3[s] . m3W + b
  {
    const int kl = tid & 31;
    float p = 0.f;
    for (int k = kl; k < 200; k += 32) {
      const u32 off = sw512((u32)ms, (u32)(2 * k));
      p += (float)(*(const f16*)(smem + S_A1H + off)) * m3W[k];
    }
#pragma unroll
    for (int d = 16; d > 0; d >>= 1) p += __shfl_down(p, d, 32);
    if (kl == 0) out[bbase + ms] = p + m3b[0];
  }
}

// ===========================================================================
extern "C" void kernel_launch(void* const* d_in, const int* in_sizes, int n_in,
                              void* d_out, int out_size, void* d_ws, size_t ws_size,
                              hipStream_t stream) {
  const int*   x_ops    = (const int*)  d_in[0];
  const float* x_adj    = (const float*)d_in[1];
  const float* op_tbl   = (const float*)d_in[3];
  const float* in_op    = (const float*)d_in[4];
  const float* out_op   = (const float*)d_in[5];
  const float* in_node  = (const float*)d_in[6];
  const float* oth_node = (const float*)d_in[7];
  const float* xh_W     = (const float*)d_in[8];
  const float* xh_b     = (const float*)d_in[9];
  const float* g0W      = (const float*)d_in[10];
  const float* g0attW   = (const float*)d_in[11];
  const float* g0attb   = (const float*)d_in[12];
  const float* g0bias   = (const float*)d_in[13];
  const float* gW       = (const float*)d_in[14];
  const float* gattW    = (const float*)d_in[15];
  const float* gattb    = (const float*)d_in[16];
  const float* gbias    = (const float*)d_in[17];
  const float* m0W = (const float*)d_in[18], *m0b = (const float*)d_in[19];
  const float* m1W = (const float*)d_in[20], *m1b = (const float*)d_in[21];
  const float* m2W = (const float*)d_in[22], *m2b = (const float*)d_in[23];
  const float* m3W = (const float*)d_in[24], *m3b = (const float*)d_in[25];
  float* out = (float*)d_out;
  char* ws = (char*)d_ws;
  (void)ws_size; (void)n_in; (void)out_size;

  const int B = in_sizes[0] / V;
  const int nblk = B / NB;

  hipFuncSetAttribute((const void*)gin_main_kernel,
                      hipFuncAttributeMaxDynamicSharedMemorySize, (int)S_TOTAL);

  hipLaunchKernelGGL(precompute_kernel, dim3(214), dim3(256), 0, stream,
                     op_tbl, in_op, out_op, in_node, oth_node, xh_W, xh_b,
                     g0W, g0attW, g0attb, gattW, gattb, gW, m0W, m1W, m2W, ws);
  hipLaunchKernelGGL(gin_main_kernel, dim3(nblk), dim3(256), (int)S_TOTAL, stream,
                     x_ops, x_adj, (const char*)ws, g0bias, gbias,
                     m0b, m1b, m2b, m3W, m3b, out);
}

// Round 7
// 465.057 us; speedup vs baseline: 1.6091x; 1.4154x over previous
//
#include <hip/hip_runtime.h>
#include <math.h>

#define V 7
#define OPD 48
#define HID 96
#define GD 128
#define NGATE 34
#define NONE_OP 3
#define NB 16

typedef unsigned short u16;
typedef unsigned int u32;
typedef _Float16 f16;
typedef __attribute__((ext_vector_type(4))) _Float16 f16x4;
typedef __attribute__((ext_vector_type(8))) _Float16 f16x8;
typedef __attribute__((ext_vector_type(4))) float f32x4;

#define RSCALE 2048.0f
#define RINV   (1.0f/2048.0f)

// ---- workspace byte offsets ----
#define WS_GATES   0u        // [5][34][128] f32
#define WS_SUP0T   87040u    // [128 cols][8 v] f32 (transposed, v=7 zero)
#define WS_GWH     91136u    // [4][128 n][128 k] f16 hi
#define WS_GWL     222208u   // lo * 2048
#define WS_W0H     353280u   // [208][128] f16
#define WS_W0L     406528u
#define WS_W1H     459776u   // [208][224] f16
#define WS_W1L     552960u
#define WS_W2H     646144u
#define WS_W2L     739328u

// ---- LDS byte offsets (dynamic, 69632 B -> 2 blocks/CU, 16 waves/CU) ----
#define S_YH   0u        // [128][128] f16, sw256 (rows = slot*8+v)
#define S_YL   32768u
#define S_SUPT 0u        // ALIAS over Y: [128 cols][128 rows] f32, ssw
#define S_ADJ  65536u    // [16][7][8] f32
#define S_GI   69120u    // [16][8] int
#define S_TOTAL 69632u
// post-GCN aliases inside the Y region:
#define S_ZH   0u        // [16][128] f16, sw256 (all 16 rows real data)
#define S_ZL   4096u
#define S_A1H  8192u     // [16][256] f16, sw512
#define S_A1L  16384u
#define S_A2H  24576u    // hi only (L2 is 2-pass)

__device__ __forceinline__ u32 sw256(u32 row, u32 kb) { return row * 256u + (kb ^ ((row & 7u) << 4)); }
__device__ __forceinline__ u32 sw512(u32 row, u32 kb) { return row * 512u + (kb ^ ((row & 7u) << 4)); }
__device__ __forceinline__ u32 ssw(u32 col, u32 rb) { return col * 512u + (rb ^ (((col ^ (col >> 3)) & 7u) << 4)); }

#define MFMA(a, b, c) __builtin_amdgcn_mfma_f32_16x16x32_f16(a, b, c, 0, 0, 0)

// ===========================================================================
// Precompute: gate tables, transposed support0, split/transposed f16 weights.
// ===========================================================================
__global__ __launch_bounds__(256) void precompute_kernel(
    const float* __restrict__ op_tbl, const float* __restrict__ in_op,
    const float* __restrict__ out_op, const float* __restrict__ in_node,
    const float* __restrict__ other_node, const float* __restrict__ xh_W,
    const float* __restrict__ xh_b, const float* __restrict__ g0W,
    const float* __restrict__ g0attW, const float* __restrict__ g0attb,
    const float* __restrict__ gattW, const float* __restrict__ gattb,
    const float* __restrict__ gW, const float* __restrict__ m0W,
    const float* __restrict__ m1W, const float* __restrict__ m2W,
    char* __restrict__ ws)
{
  const int blk = blockIdx.x, tid = threadIdx.x;
  float* gates = (float*)(ws + WS_GATES);
  float* sup0T = (float*)(ws + WS_SUP0T);
  if (blk < 85) {                       // 170 gate rows, 2 per block
    const int row = blk * 2 + (tid >> 7);
    const int c = tid & 127;
    const int l = row / NGATE, e = row % NGATE;
    const float* emb = (e < 32) ? (op_tbl + e * OPD) : (e == 32 ? in_op : out_op);
    const float* aW = (l == 0) ? g0attW : (gattW + (size_t)(l - 1) * OPD * GD);
    const float* ab = (l == 0) ? g0attb : (gattb + (l - 1) * GD);
    float acc = ab[c];
    for (int j = 0; j < OPD; j++) acc += emb[j] * aW[j * GD + c];
    gates[(size_t)row * GD + c] = 1.0f / (1.0f + expf(-acc));
  } else if (blk == 85) {               // support0 -> transposed [col][8]
    __shared__ float x[V * HID];
    for (int i = tid; i < V * HID; i += 256) {
      const int v = i / HID, h = i % HID;
      const float* emb = (v == 0) ? in_node : other_node;
      float acc = xh_b[h];
      for (int j = 0; j < 48; j++) acc += emb[j] * xh_W[j * HID + h];
      x[i] = acc;
    }
    __syncthreads();
    for (int i = tid; i < V * GD; i += 256) {
      const int v = i / GD, c = i % GD;
      float acc = 0.f;
      for (int h = 0; h < HID; h++) acc += x[v * HID + h] * g0W[h * GD + c];
      sup0T[c * 8 + v] = acc;
    }
    for (int i = tid; i < GD; i += 256) sup0T[i * 8 + 7] = 0.f;
  } else {                              // weight split+transpose (f16 hi/lo)
    for (int idx = (blk - 86) * 256 + tid; idx < 185344; idx += 128 * 256) {
      float w; f16 *ph, *pl;
      if (idx < 65536) {
        const int l = idx >> 14, rem = idx & 16383;
        const int n = rem >> 7, k = rem & 127;
        w = gW[(size_t)l * 16384 + k * 128 + n];
        ph = (f16*)(ws + WS_GWH) + idx; pl = (f16*)(ws + WS_GWL) + idx;
      } else if (idx < 92160) {
        const int j = idx - 65536, n = j >> 7, k = j & 127;
        w = (n < 200) ? m0W[(size_t)k * 200 + n] : 0.f;
        ph = (f16*)(ws + WS_W0H) + j; pl = (f16*)(ws + WS_W0L) + j;
      } else if (idx < 138752) {
        const int j = idx - 92160, n = j / 224, k = j % 224;
        w = (n < 200 && k < 200) ? m1W[(size_t)k * 200 + n] : 0.f;
        ph = (f16*)(ws + WS_W1H) + j; pl = (f16*)(ws + WS_W1L) + j;
      } else {
        const int j = idx - 138752, n = j / 224, k = j % 224;
        w = (n < 200 && k < 200) ? m2W[(size_t)k * 200 + n] : 0.f;
        ph = (f16*)(ws + WS_W2H) + j; pl = (f16*)(ws + WS_W2L) + j;
      }
      const f16 h = (f16)w;
      *ph = h;
      *pl = (f16)((w - (float)h) * RSCALE);
    }
  }
}

// ===========================================================================
// Main fused kernel. 512 threads = 8 waves, 16 slots/block, row = s*8 + v
// (M=128). One Y/SUPT buffer shared by 8 waves -> 2 blocks/CU = 16 waves/CU.
// ===========================================================================
__global__ __launch_bounds__(512, 4) void gin_main_kernel(
    const int* __restrict__ x_ops, const float* __restrict__ x_adj,
    const char* __restrict__ ws,
    const float* __restrict__ g0_bias, const float* __restrict__ gcn_bias,
    const float* __restrict__ m0b, const float* __restrict__ m1b,
    const float* __restrict__ m2b, const float* __restrict__ m3W,
    const float* __restrict__ m3b, float* __restrict__ out)
{
  extern __shared__ char smem[];
  const int tid = threadIdx.x;
  const int bbase = blockIdx.x * NB;
  const float* gates_ws = (const float*)(ws + WS_GATES);
  const float* sup0T = (const float*)(ws + WS_SUP0T);
  const f16* GWH = (const f16*)(ws + WS_GWH);
  const f16* GWL = (const f16*)(ws + WS_GWL);
  const f16* W0H = (const f16*)(ws + WS_W0H);
  const f16* W0L = (const f16*)(ws + WS_W0L);
  const f16* W1H = (const f16*)(ws + WS_W1H);
  const f16* W1L = (const f16*)(ws + WS_W1L);
  const f16* W2H = (const f16*)(ws + WS_W2H);
  const f16* W2L = (const f16*)(ws + WS_W2L);

  // ---- prologue: adj^T + gate indices ----
  for (int i = tid; i < NB * 56; i += 512) {
    const int s = i / 56, r = i % 56, v = r >> 3, w = r & 7;
    ((float*)(smem + S_ADJ))[i] = (w < 7) ? x_adj[(size_t)(bbase + s) * 49 + w * 7 + v] : 0.f;
  }
  if (tid < 128) {
    const int s = tid >> 3, v = tid & 7;
    const int g = (v == 0) ? 32 : (v == 6) ? 33 : (v == 7) ? 0
                : x_ops[(size_t)(bbase + s) * 7 + v];
    ((int*)(smem + S_GI))[tid] = g;
  }
  __syncthreads();

  const int lane = tid & 63, wave = tid >> 6;   // wave 0..7
  const int lrow = lane & 15, lq = lane >> 4;
  const int ms = tid >> 5;            // mix: slot 0..15
  const int colbase = (tid & 31) * 4; // mix: 4 cols per thread

  // =================== GCN layers ===================
  for (int l = 0; l < 5; l++) {
    if (l > 0) {
      const f16* wh = GWH + (l - 1) * 16384;
      const f16* wl = GWL + (l - 1) * 16384;
      f32x4 acc0[8], acc1[8];
#pragma unroll
      for (int t = 0; t < 8; t++) {
        acc0[t] = (f32x4){0.f, 0.f, 0.f, 0.f};
        acc1[t] = (f32x4){0.f, 0.f, 0.f, 0.f};
      }
#pragma unroll
      for (int ks = 0; ks < 4; ks++) {
        const int eo = (wave * 16 + lrow) * 128 + ks * 32 + lq * 8;
        const f16x8 bh = *(const f16x8*)(wh + eo);
        const f16x8 bl = *(const f16x8*)(wl + eo);
#pragma unroll
        for (int t = 0; t < 8; t++) {
          const u32 off = sw256((u32)(t * 16 + lrow), (u32)(ks * 64 + lq * 16));
          const f16x8 ah = *(const f16x8*)(smem + S_YH + off);
          const f16x8 al = *(const f16x8*)(smem + S_YL + off);
          acc0[t] = MFMA(ah, bh, acc0[t]);
          acc1[t] = MFMA(ah, bl, acc1[t]);
          acc1[t] = MFMA(al, bh, acc1[t]);
        }
      }
      __syncthreads();   // all waves done reading Y; SUPT may clobber it
      {
        const u32 col = (u32)(wave * 16 + lrow);
#pragma unroll
        for (int t = 0; t < 8; t++) {
          f32x4 vv;
#pragma unroll
          for (int r = 0; r < 4; r++) vv[r] = acc0[t][r] + acc1[t][r] * RINV;
          *(f32x4*)(smem + S_SUPT + ssw(col, (u32)(t * 64 + lq * 16))) = vv;
        }
      }
      __syncthreads();
    }

    // ---- phase C: load support for (slot, 4 cols) into regs ----
    f32x4 sa[4], sb[4];
    if (l == 0) {
#pragma unroll
      for (int c = 0; c < 4; c++) {
        const float* p = sup0T + (size_t)(colbase + c) * 8;
        sa[c] = *(const f32x4*)p;
        sb[c] = *(const f32x4*)(p + 4);
      }
    } else {
#pragma unroll
      for (int c = 0; c < 4; c++) {
        const u32 col = (u32)(colbase + c);
        sa[c] = *(const f32x4*)(smem + S_SUPT + ssw(col, (u32)(ms * 32)));
        sb[c] = *(const f32x4*)(smem + S_SUPT + ssw(col, (u32)(ms * 32 + 16)));
      }
      __syncthreads();   // SUPT in regs; Y region may be rewritten
    }

    // ---- phase D: adjmix + gate + residual + bias ----
    {
      const float* bias_l = (l == 0) ? g0_bias : gcn_bias + (l - 1) * GD;
      const f32x4 bb = *(const f32x4*)(bias_l + colbase);
      const int* giv = (const int*)(smem + S_GI) + ms * 8;
      float zacc[4];
#pragma unroll
      for (int c = 0; c < 4; c++) zacc[c] = 0.f;
#pragma unroll
      for (int v = 0; v < 7; v++) {
        const f32x4 a0 = *(const f32x4*)(smem + S_ADJ + (ms * 56 + v * 8) * 4);
        const f32x4 a1 = *(const f32x4*)(smem + S_ADJ + (ms * 56 + v * 8) * 4 + 16);
        const int gidx = giv[v];
        const f32x4 gg = *(const f32x4*)(gates_ws + ((size_t)l * NGATE + gidx) * GD + colbase);
        float y[4];
#pragma unroll
        for (int c = 0; c < 4; c++) {
          const float t = a0[0] * sa[c][0] + a0[1] * sa[c][1] + a0[2] * sa[c][2] + a0[3] * sa[c][3]
                        + a1[0] * sb[c][0] + a1[1] * sb[c][1] + a1[2] * sb[c][2];
          const float sv = (v < 4) ? sa[c][v] : sb[c][v - 4];
          y[c] = gg[c] * t + sv + bb[c];
        }
        if (l < 4) {
          union { f16x4 v4; f16 e[4]; } ph, pl;
#pragma unroll
          for (int c = 0; c < 4; c++) {
            const float r = fmaxf(y[c], 0.f);
            const f16 h = (f16)r;
            ph.e[c] = h;
            pl.e[c] = (f16)((r - (float)h) * RSCALE);
          }
          const u32 yo = sw256((u32)(ms * 8 + v), (u32)(colbase * 2));
          *(f16x4*)(smem + S_YH + yo) = ph.v4;
          *(f16x4*)(smem + S_YL + yo) = pl.v4;
        } else {
          if ((v == 6) || (v >= 1 && gidx != NONE_OP))
#pragma unroll
            for (int c = 0; c < 4; c++) zacc[c] += y[c];
        }
      }
      if (l == 4) {
        union { f16x4 v4; f16 e[4]; } ph, pl;
#pragma unroll
        for (int c = 0; c < 4; c++) {
          const float z = zacc[c] * (1.f / 6.f);
          const f16 h = (f16)z;
          ph.e[c] = h;
          pl.e[c] = (f16)((z - (float)h) * RSCALE);
        }
        const u32 zo = sw256((u32)ms, (u32)(colbase * 2));
        *(f16x4*)(smem + S_ZH + zo) = ph.v4;
        *(f16x4*)(smem + S_ZL + zo) = pl.v4;
        // Zero the MLP act region (aliases dead SUPT f32; stale bytes read
        // as f16 can be Inf/NaN -> Inf*0 poisons valid accumulators).
        for (int i = tid; i < 6144; i += 512)
          ((u32*)(smem + S_A1H))[i] = 0u;          // A1H, A1L, A2H (24 KB)
      }
    }
    __syncthreads();
  }

  // =================== MLP ===================
  // L0: Z(16x128) @ W0t -> A1 (hi+lo).  wave handles nt in {wave, wave+8}.
  {
    f32x4 macc0[2], macc1[2];
#pragma unroll
    for (int i = 0; i < 2; i++) { macc0[i] = (f32x4){0.f,0.f,0.f,0.f}; macc1[i] = (f32x4){0.f,0.f,0.f,0.f}; }
#pragma unroll
    for (int ks = 0; ks < 4; ks++) {
      const u32 off = sw256((u32)lrow, (u32)(ks * 64 + lq * 16));
      const f16x8 zh = *(const f16x8*)(smem + S_ZH + off);
      const f16x8 zl = *(const f16x8*)(smem + S_ZL + off);
#pragma unroll
      for (int i = 0; i < 2; i++) {
        const int nt = wave + i * 8;
        if (nt < 13) {
          const int eo = (nt * 16 + lrow) * 128 + ks * 32 + lq * 8;
          const f16x8 wh8 = *(const f16x8*)(W0H + eo);
          const f16x8 wl8 = *(const f16x8*)(W0L + eo);
          macc0[i] = MFMA(zh, wh8, macc0[i]);
          macc1[i] = MFMA(zh, wl8, macc1[i]);
          macc1[i] = MFMA(zl, wh8, macc1[i]);
        }
      }
    }
#pragma unroll
    for (int i = 0; i < 2; i++) {
      const int nt = wave + i * 8;
      if (nt < 13) {
        const int col = nt * 16 + lrow;
        const float b = (col < 200) ? m0b[col] : 0.f;
#pragma unroll
        for (int r = 0; r < 4; r++) {
          const float a = fmaxf(macc0[i][r] + macc1[i][r] * RINV + b, 0.f);
          const f16 h = (f16)a;
          const u32 off = sw512((u32)(lq * 4 + r), (u32)(2 * col));
          *(f16*)(smem + S_A1H + off) = h;
          *(f16*)(smem + S_A1L + off) = (f16)((a - (float)h) * RSCALE);
        }
      }
    }
  }
  __syncthreads();
  // L1: A1(16x224) @ W1t -> A2 (hi only)
  {
    f32x4 macc0[2], macc1[2];
#pragma unroll
    for (int i = 0; i < 2; i++) { macc0[i] = (f32x4){0.f,0.f,0.f,0.f}; macc1[i] = (f32x4){0.f,0.f,0.f,0.f}; }
#pragma unroll
    for (int ks = 0; ks < 7; ks++) {
      const u32 off = sw512((u32)lrow, (u32)(ks * 64 + lq * 16));
      const f16x8 ah = *(const f16x8*)(smem + S_A1H + off);
      const f16x8 al = *(const f16x8*)(smem + S_A1L + off);
#pragma unroll
      for (int i = 0; i < 2; i++) {
        const int nt = wave + i * 8;
        if (nt < 13) {
          const int eo = (nt * 16 + lrow) * 224 + ks * 32 + lq * 8;
          const f16x8 wh8 = *(const f16x8*)(W1H + eo);
          const f16x8 wl8 = *(const f16x8*)(W1L + eo);
          macc0[i] = MFMA(ah, wh8, macc0[i]);
          macc1[i] = MFMA(ah, wl8, macc1[i]);
          macc1[i] = MFMA(al, wh8, macc1[i]);
        }
      }
    }
    __syncthreads();   // all waves done reading A1 before A2 write epoch ends
#pragma unroll
    for (int i = 0; i < 2; i++) {
      const int nt = wave + i * 8;
      if (nt < 13) {
        const int col = nt * 16 + lrow;
        const float b = (col < 200) ? m1b[col] : 0.f;
#pragma unroll
        for (int r = 0; r < 4; r++) {
          const float a = fmaxf(macc0[i][r] + macc1[i][r] * RINV + b, 0.f);
          const u32 off = sw512((u32)(lq * 4 + r), (u32)(2 * col));
          *(f16*)(smem + S_A2H + off) = (f16)a;
        }
      }
    }
  }
  __syncthreads();
  // L2: A2(hi only) @ W2t (2-pass) -> A3 (reuses A1H region, disjoint from A2H)
  {
    f32x4 macc0[2], macc1[2];
#pragma unroll
    for (int i = 0; i < 2; i++) { macc0[i] = (f32x4){0.f,0.f,0.f,0.f}; macc1[i] = (f32x4){0.f,0.f,0.f,0.f}; }
#pragma unroll
    for (int ks = 0; ks < 7; ks++) {
      const u32 off = sw512((u32)lrow, (u32)(ks * 64 + lq * 16));
      const f16x8 ah = *(const f16x8*)(smem + S_A2H + off);
#pragma unroll
      for (int i = 0; i < 2; i++) {
        const int nt = wave + i * 8;
        if (nt < 13) {
          const int eo = (nt * 16 + lrow) * 224 + ks * 32 + lq * 8;
          const f16x8 wh8 = *(const f16x8*)(W2H + eo);
          const f16x8 wl8 = *(const f16x8*)(W2L + eo);
          macc0[i] = MFMA(ah, wh8, macc0[i]);
          macc1[i] = MFMA(ah, wl8, macc1[i]);
        }
      }
    }
#pragma unroll
    for (int i = 0; i < 2; i++) {
      const int nt = wave + i * 8;
      if (nt < 13) {
        const int col = nt * 16 + lrow;
        const float b = (col < 200) ? m2b[col] : 0.f;
#pragma unroll
        for (int r = 0; r < 4; r++) {
          const float a = fmaxf(macc0[i][r] + macc1[i][r] * RINV + b, 0.f);
          const u32 off = sw512((u32)(lq * 4 + r), (u32)(2 * col));
          *(f16*)(smem + S_A1H + off) = (f16)a;
        }
      }
    }
  }
  __syncthreads();
  // final: out[s] = A3[s] . m3W + b
  {
    const int kl = tid & 31;
    float p = 0.f;
    for (int k = kl; k < 200; k += 32) {
      const u32 off = sw512((u32)ms, (u32)(2 * k));
      p += (float)(*(const f16*)(smem + S_A1H + off)) * m3W[k];
    }
#pragma unroll
    for (int d = 16; d > 0; d >>= 1) p += __shfl_down(p, d, 32);
    if (kl == 0) out[bbase + ms] = p + m3b[0];
  }
}

// ===========================================================================
extern "C" void kernel_launch(void* const* d_in, const int* in_sizes, int n_in,
                              void* d_out, int out_size, void* d_ws, size_t ws_size,
                              hipStream_t stream) {
  const int*   x_ops    = (const int*)  d_in[0];
  const float* x_adj    = (const float*)d_in[1];
  const float* op_tbl   = (const float*)d_in[3];
  const float* in_op    = (const float*)d_in[4];
  const float* out_op   = (const float*)d_in[5];
  const float* in_node  = (const float*)d_in[6];
  const float* oth_node = (const float*)d_in[7];
  const float* xh_W     = (const float*)d_in[8];
  const float* xh_b     = (const float*)d_in[9];
  const float* g0W      = (const float*)d_in[10];
  const float* g0attW   = (const float*)d_in[11];
  const float* g0attb   = (const float*)d_in[12];
  const float* g0bias   = (const float*)d_in[13];
  const float* gW       = (const float*)d_in[14];
  const float* gattW    = (const float*)d_in[15];
  const float* gattb    = (const float*)d_in[16];
  const float* gbias    = (const float*)d_in[17];
  const float* m0W = (const float*)d_in[18], *m0b = (const float*)d_in[19];
  const float* m1W = (const float*)d_in[20], *m1b = (const float*)d_in[21];
  const float* m2W = (const float*)d_in[22], *m2b = (const float*)d_in[23];
  const float* m3W = (const float*)d_in[24], *m3b = (const float*)d_in[25];
  float* out = (float*)d_out;
  char* ws = (char*)d_ws;
  (void)ws_size; (void)n_in; (void)out_size;

  const int B = in_sizes[0] / V;
  const int nblk = B / NB;

  hipFuncSetAttribute((const void*)gin_main_kernel,
                      hipFuncAttributeMaxDynamicSharedMemorySize, (int)S_TOTAL);

  hipLaunchKernelGGL(precompute_kernel, dim3(214), dim3(256), 0, stream,
                     op_tbl, in_op, out_op, in_node, oth_node, xh_W, xh_b,
                     g0W, g0attW, g0attb, gattW, gattb, gW, m0W, m1W, m2W, ws);
  hipLaunchKernelGGL(gin_main_kernel, dim3(nblk), dim3(512), (int)S_TOTAL, stream,
                     x_ops, x_adj, (const char*)ws, g0bias, gbias,
                     m0b, m1b, m2b, m3W, m3b, out);
}